// Round 9
// baseline (376.479 us; speedup 1.0000x reference)
//
#include <hip/hip_runtime.h>
#include <hip/hip_fp16.h>

#define BB 32
#define NN 4096
#define EE 65536
#define DS 8
#define ES 4
#define ENC 8
#define HH 16
#define OUTC 4
#define NI (NN * DS)
#define ROW (NN * OUTC - OUTC + 1)   // 16381 per-batch output row length
#define ESPLIT 8                     // edge-chunk splits per batch
#define EPB (EE / ESPLIT)            // 8192 edges per block
#define CUNITS (BB * 64)             // 2048 critic wave-units, 512 rows each

typedef __fp16 half2_t __attribute__((ext_vector_type(2)));

// ============ Kernel 1: node-enc (in-LDS f16 x) + wave-split {edge scatter | critic GEMV} ============
// grid = 256 blocks x 1024 threads, 1 block/CU (128KB+ LDS).
// Block p -> L=(p&7)*32+(p>>3) -> (b = L>>3, s = L&7): the 8 s-chunks of batch b share an XCD.
// Waves 0-7: 8192 edges (gather x from LDS, 4 packed-f16 DS atomics/edge).
// Waves 8-15: critic partials (hide under the DS-atomic wall).
__global__ __launch_bounds__(1024, 4) void k_mega(
    const float* __restrict__ obs,
    const float* __restrict__ Wne1, const float* __restrict__ bne1,
    const float* __restrict__ Wne2, const float* __restrict__ bne2,
    const float* __restrict__ eattr,
    const int* __restrict__ eidx,
    const float* __restrict__ Wee, const float* __restrict__ bee,
    const float* __restrict__ obsf, const float* __restrict__ Wc1,
    float* __restrict__ partial,        // [BB*ESPLIT][NN][ENC] f32
    uint32_t* __restrict__ xg,          // [BB][NN][4] f16x2
    float* __restrict__ hpart) {        // [CUNITS][HH]
  __shared__ uint32_t xl[NN * 4];       // 64 KB: x[node] as 4x f16x2 (16 B/node)
  __shared__ uint32_t sagg[4 * NN];     // 64 KB: agg accumulator [cp][node] f16x2
  __shared__ float sWn1[DS * HH], sbn1[HH], sWn2[HH * ENC], sbn2[ENC];

  int p = blockIdx.x;
  int L = (p & 7) * 32 + (p >> 3);
  int b = L >> 3, s = L & 7;
  int t = threadIdx.x;
  int wv = t >> 6, lane = t & 63;

  // ---- stage A: weights->LDS, zero sagg, compute x into LDS (f16) ----
  if (t < DS * HH)  sWn1[t] = Wne1[t];
  if (t < HH)       sbn1[t] = bne1[t];
  if (t < HH * ENC) sWn2[t] = Wne2[t];
  if (t < ENC)      sbn2[t] = bne2[t];
  {
    uint4 z = make_uint4(0u, 0u, 0u, 0u);
    uint4* sz = (uint4*)sagg;
#pragma unroll
    for (int i = 0; i < 4; ++i) sz[t + i * 1024] = z;
  }
  __syncthreads();

#pragma unroll
  for (int i = 0; i < 4; ++i) {
    int n = t + i * 1024;
    const float4* op = (const float4*)(obs + ((size_t)b * NN + n) * DS);
    float4 o0 = op[0], o1 = op[1];
    float o[DS] = {o0.x, o0.y, o0.z, o0.w, o1.x, o1.y, o1.z, o1.w};
    float hb[HH];
#pragma unroll
    for (int j = 0; j < HH; ++j) {
      float a = sbn1[j];
#pragma unroll
      for (int k2 = 0; k2 < DS; ++k2) a += o[k2] * sWn1[k2 * HH + j];
      hb[j] = fmaxf(a, 0.f);
    }
    float e[ENC];
#pragma unroll
    for (int c = 0; c < ENC; ++c) {
      float a = sbn2[c];
#pragma unroll
      for (int j = 0; j < HH; ++j) a += hb[j] * sWn2[j * ENC + c];
      e[c] = a;
    }
    uint4 pk;
    pk.x = __builtin_bit_cast(uint32_t, __builtin_amdgcn_cvt_pkrtz(e[0], e[1]));
    pk.y = __builtin_bit_cast(uint32_t, __builtin_amdgcn_cvt_pkrtz(e[2], e[3]));
    pk.z = __builtin_bit_cast(uint32_t, __builtin_amdgcn_cvt_pkrtz(e[4], e[5]));
    pk.w = __builtin_bit_cast(uint32_t, __builtin_amdgcn_cvt_pkrtz(e[6], e[7]));
    *(uint4*)(&xl[n * 4]) = pk;
  }
  __syncthreads();

  // ---- stage B: wave-split ----
  if (wv < 8) {
    // edge waves: 1024 edges each, 16/lane in 4 ILP-groups of 4
    float wvv[ES * ENC], bvv[ENC];
#pragma unroll
    for (int i = 0; i < ES * ENC; ++i) wvv[i] = Wee[i];
#pragma unroll
    for (int c = 0; c < ENC; ++c) bvv[c] = bee[c];

    const int*    ibs = eidx + (size_t)b * 2 * EE + (size_t)s * EPB + wv * 1024;
    const int*    ibd = ibs + EE;
    const float4* ab4 = (const float4*)eattr + (size_t)b * EE + (size_t)s * EPB + wv * 1024;

#pragma unroll
    for (int g = 0; g < 4; ++g) {
      int s_[4], d_[4];
      float4 a_[4];
#pragma unroll
      for (int u = 0; u < 4; ++u) {
        int k = g * 256 + u * 64 + lane;
        s_[u] = ibs[k]; d_[u] = ibd[k];
      }
#pragma unroll
      for (int u = 0; u < 4; ++u) a_[u] = ab4[g * 256 + u * 64 + lane];
      uint4 xp_[4];
#pragma unroll
      for (int u = 0; u < 4; ++u) xp_[u] = *(const uint4*)(&xl[s_[u] * 4]);
#pragma unroll
      for (int u = 0; u < 4; ++u) {
        half2_t h0 = __builtin_bit_cast(half2_t, xp_[u].x);
        half2_t h1 = __builtin_bit_cast(half2_t, xp_[u].y);
        half2_t h2 = __builtin_bit_cast(half2_t, xp_[u].z);
        half2_t h3 = __builtin_bit_cast(half2_t, xp_[u].w);
        float xv[ENC] = {(float)h0[0], (float)h0[1], (float)h1[0], (float)h1[1],
                         (float)h2[0], (float)h2[1], (float)h3[0], (float)h3[1]};
        float av[ES] = {a_[u].x, a_[u].y, a_[u].z, a_[u].w};
        float m[ENC];
#pragma unroll
        for (int c = 0; c < ENC; ++c) {
          float ea = bvv[c];
#pragma unroll
          for (int i2 = 0; i2 < ES; ++i2) ea += av[i2] * wvv[i2 * ENC + c];
          m[c] = fmaxf(xv[c] + ea, 0.f);
        }
        uint32_t base = (uint32_t)(uintptr_t)(&sagg[d_[u]]);
#pragma unroll
        for (int cp = 0; cp < 4; ++cp) {
          half2_t pk = __builtin_amdgcn_cvt_pkrtz(m[2 * cp], m[2 * cp + 1]);
          uint32_t pku = __builtin_bit_cast(uint32_t, pk);
          uint32_t addr = base + (uint32_t)(cp * NN * 4);
          asm volatile("ds_pk_add_f16 %0, %1" :: "v"(addr), "v"(pku) : "memory");
        }
      }
    }
  } else {
    // critic waves: unit uw covers 512 rows of batch cb; 8 rows/lane
    int uw = p * 8 + (wv - 8);            // 0..2047
    int cb = uw >> 6, q = uw & 63;
    const float* ob = obsf + (size_t)cb * NI;
    float acc[HH];
#pragma unroll
    for (int j = 0; j < HH; ++j) acc[j] = 0.f;
#pragma unroll
    for (int i = 0; i < 8; ++i) {
      int r = q * 512 + i * 64 + lane;
      float v = ob[r];
      const float4* wr = (const float4*)(Wc1 + (size_t)r * HH);
      float4 w0 = wr[0], w1 = wr[1], w2 = wr[2], w3 = wr[3];
      acc[0]  += v * w0.x; acc[1]  += v * w0.y; acc[2]  += v * w0.z; acc[3]  += v * w0.w;
      acc[4]  += v * w1.x; acc[5]  += v * w1.y; acc[6]  += v * w1.z; acc[7]  += v * w1.w;
      acc[8]  += v * w2.x; acc[9]  += v * w2.y; acc[10] += v * w2.z; acc[11] += v * w2.w;
      acc[12] += v * w3.x; acc[13] += v * w3.y; acc[14] += v * w3.z; acc[15] += v * w3.w;
    }
#pragma unroll
    for (int j = 0; j < HH; ++j) {
#pragma unroll
      for (int mres = 1; mres < 64; mres <<= 1) acc[j] += __shfl_xor(acc[j], mres, 64);
    }
    if (lane < HH) hpart[(size_t)uw * HH + lane] = acc[lane];
  }
  __syncthreads();

  // ---- stage C: flush agg partial (f32) + x (s==0 only) ----
  float* pb = partial + (size_t)L * NN * ENC;
#pragma unroll
  for (int i = 0; i < 4; ++i) {
    int n = t + i * 1024;
    uint32_t w0 = sagg[0 * NN + n], w1 = sagg[1 * NN + n];
    uint32_t w2 = sagg[2 * NN + n], w3 = sagg[3 * NN + n];
    half2_t h0 = __builtin_bit_cast(half2_t, w0);
    half2_t h1 = __builtin_bit_cast(half2_t, w1);
    half2_t h2 = __builtin_bit_cast(half2_t, w2);
    half2_t h3 = __builtin_bit_cast(half2_t, w3);
    float4 lo = make_float4((float)h0[0], (float)h0[1], (float)h1[0], (float)h1[1]);
    float4 hi = make_float4((float)h2[0], (float)h2[1], (float)h3[0], (float)h3[1]);
    float4* dp = (float4*)(pb + (size_t)n * ENC);
    dp[0] = lo; dp[1] = hi;
  }
  if (s == 0) {
    uint4* xg4 = (uint4*)xg + (size_t)b * NN;
#pragma unroll
    for (int i = 0; i < 4; ++i) {
      int n = t + i * 1024;
      xg4[n] = *(uint4*)(&xl[n * 4]);
    }
  }
}

// ============ Kernel 2: actor head (blocks 0..511) + critic finish (block 512) ============
__global__ __launch_bounds__(256) void k_tail(
    const uint32_t* __restrict__ xg, const float* __restrict__ partial,
    const float* __restrict__ Wa1, const float* __restrict__ ba1,
    const float* __restrict__ Wa2, const float* __restrict__ ba2,
    const float* __restrict__ hpart,
    const float* __restrict__ bc1,
    const float* __restrict__ Wc2, const float* __restrict__ bc2,
    float* __restrict__ out) {
  int t = threadIdx.x;
  if (blockIdx.x == 512) {
    if (t < BB) {
      int b = t;
      float hsum[HH];
#pragma unroll
      for (int j = 0; j < HH; ++j) hsum[j] = bc1[j];
      for (int u = 0; u < 64; ++u) {
        const float* hp = hpart + (size_t)(b * 64 + u) * HH;
#pragma unroll
        for (int j = 0; j < HH; ++j) hsum[j] += hp[j];
      }
      float val = bc2[0];
#pragma unroll
      for (int j = 0; j < HH; ++j) val += fmaxf(hsum[j], 0.f) * Wc2[j];
      out[(size_t)b * ROW + (ROW - 1)] = val;
    }
    return;
  }
  __shared__ float sW1[ENC * HH], sb1[HH], sW2[HH * OUTC], sb2[OUTC];
  if (t < ENC * HH)  sW1[t] = Wa1[t];
  if (t < HH)        sb1[t] = ba1[t];
  if (t < HH * OUTC) sW2[t] = Wa2[t];
  if (t < OUTC)      sb2[t] = ba2[t];
  __syncthreads();
  int gid = blockIdx.x * 256 + t;
  int b = gid >> 12;                         // N = 4096
  int n = gid & (NN - 1);

  uint4 xp = ((const uint4*)xg)[gid];
  half2_t x0 = __builtin_bit_cast(half2_t, xp.x);
  half2_t x1 = __builtin_bit_cast(half2_t, xp.y);
  half2_t x2 = __builtin_bit_cast(half2_t, xp.z);
  half2_t x3 = __builtin_bit_cast(half2_t, xp.w);
  float v[ENC] = {(float)x0[0], (float)x0[1], (float)x1[0], (float)x1[1],
                  (float)x2[0], (float)x2[1], (float)x3[0], (float)x3[1]};
  const float* pb = partial + ((size_t)(b * ESPLIT) * NN + n) * ENC;
#pragma unroll
  for (int s = 0; s < ESPLIT; ++s) {
    const float4* pp = (const float4*)(pb + (size_t)s * NN * ENC);
    float4 lo = pp[0], hi = pp[1];
    v[0] += lo.x; v[1] += lo.y; v[2] += lo.z; v[3] += lo.w;
    v[4] += hi.x; v[5] += hi.y; v[6] += hi.z; v[7] += hi.w;
  }

  float hb[HH];
#pragma unroll
  for (int j = 0; j < HH; ++j) {
    float a = sb1[j];
#pragma unroll
    for (int i = 0; i < ENC; ++i) a += v[i] * sW1[i * HH + j];
    hb[j] = fmaxf(a, 0.f);
  }
  float o[OUTC];
#pragma unroll
  for (int c = 0; c < OUTC; ++c) {
    float a = sb2[c];
#pragma unroll
    for (int j = 0; j < HH; ++j) a += hb[j] * sW2[j * OUTC + c];
    o[c] = a;
  }
  if (n > 0) {
    float* op = out + (size_t)b * ROW + (size_t)(n - 1) * OUTC;
    op[0] = o[0]; op[1] = o[1]; op[2] = o[2]; op[3] = o[3];
  }
}

extern "C" void kernel_launch(void* const* d_in, const int* in_sizes, int n_in,
                              void* d_out, int out_size, void* d_ws, size_t ws_size,
                              hipStream_t stream) {
  const float* agent_obs  = (const float*)d_in[0];
  const float* edge_attr  = (const float*)d_in[1];
  const float* obs_flat   = (const float*)d_in[2];
  const int*   edge_index = (const int*)d_in[3];
  const float* W_ne1 = (const float*)d_in[4];
  const float* b_ne1 = (const float*)d_in[5];
  const float* W_ne2 = (const float*)d_in[6];
  const float* b_ne2 = (const float*)d_in[7];
  const float* W_ee  = (const float*)d_in[8];
  const float* b_ee  = (const float*)d_in[9];
  const float* W_a1  = (const float*)d_in[10];
  const float* b_a1  = (const float*)d_in[11];
  const float* W_a2  = (const float*)d_in[12];
  const float* b_a2  = (const float*)d_in[13];
  const float* W_c1  = (const float*)d_in[14];
  const float* b_c1  = (const float*)d_in[15];
  const float* W_c2  = (const float*)d_in[16];
  const float* b_c2  = (const float*)d_in[17];
  float* out = (float*)d_out;

  float*    partial = (float*)d_ws;                            // 32 MB
  uint32_t* xg      = (uint32_t*)(partial + (size_t)BB * ESPLIT * NN * ENC);  // 2 MB
  float*    hpart   = (float*)(xg + (size_t)BB * NN * 4);      // 128 KB

  k_mega<<<dim3(BB * ESPLIT), dim3(1024), 0, stream>>>(
      agent_obs, W_ne1, b_ne1, W_ne2, b_ne2,
      edge_attr, edge_index, W_ee, b_ee,
      obs_flat, W_c1, partial, xg, hpart);
  k_tail<<<dim3(513), dim3(256), 0, stream>>>(
      xg, partial, W_a1, b_a1, W_a2, b_a2, hpart, b_c1, W_c2, b_c2, out);
}

// Round 11
// 368.127 us; speedup vs baseline: 1.0227x; 1.0227x over previous
//
#include <hip/hip_runtime.h>
#include <hip/hip_fp16.h>

#define BB 32
#define NN 4096
#define EE 65536
#define DS 8
#define ES 4
#define ENC 8
#define HH 16
#define OUTC 4
#define NI (NN * DS)
#define ROW (NN * OUTC - OUTC + 1)   // 16381 per-batch output row length
#define ESPLIT 8                     // edge-chunk splits per batch
#define EPB (EE / ESPLIT)            // 8192 edges per block
#define CUNITS (BB * 64)             // 2048 critic wave-units, 512 rows each

typedef __fp16 half2_t __attribute__((ext_vector_type(2)));

// ============ Kernel 1: node-enc (in-LDS f16 x) + wave-split {edge scatter | critic GEMV} ============
// grid = 256 blocks x 1024 threads, 1 block/CU (129.5 KB LDS).
// __launch_bounds__(1024, 2): VGPR cap 128 (16 waves/CU still fits) -- r9's (1024,4)=64-reg cap
// caused scratch spill (WRITE 408 MB). Edge ILP reduced to 2 to stay under 128.
__global__ __launch_bounds__(1024, 2) void k_mega(
    const float* __restrict__ obs,
    const float* __restrict__ Wne1, const float* __restrict__ bne1,
    const float* __restrict__ Wne2, const float* __restrict__ bne2,
    const float* __restrict__ eattr,
    const int* __restrict__ eidx,
    const float* __restrict__ Wee, const float* __restrict__ bee,
    const float* __restrict__ obsf, const float* __restrict__ Wc1,
    uint4* __restrict__ partial,        // [BB*ESPLIT][NN] f16x2 x4 (16 B/node)
    uint32_t* __restrict__ xg,          // [BB][NN][4] f16x2
    float* __restrict__ hpart) {        // [CUNITS][HH]
  __shared__ uint32_t xl[NN * 4];       // 64 KB: x[node] as 4x f16x2
  __shared__ uint32_t sagg[4 * NN];     // 64 KB: agg accumulator [cp][node] f16x2
  __shared__ float sWn1[DS * HH], sbn1[HH], sWn2[HH * ENC], sbn2[ENC];

  int p = blockIdx.x;
  int L = (p & 7) * 32 + (p >> 3);      // batch b pinned to XCD p&7
  int b = L >> 3, s = L & 7;
  int t = threadIdx.x;
  int wv = t >> 6, lane = t & 63;

  // ---- stage A: weights->LDS, zero sagg, compute x into LDS (f16) ----
  if (t < DS * HH)  sWn1[t] = Wne1[t];
  if (t < HH)       sbn1[t] = bne1[t];
  if (t < HH * ENC) sWn2[t] = Wne2[t];
  if (t < ENC)      sbn2[t] = bne2[t];
  {
    uint4 z = make_uint4(0u, 0u, 0u, 0u);
    uint4* sz = (uint4*)sagg;
#pragma unroll
    for (int i = 0; i < 4; ++i) sz[t + i * 1024] = z;
  }
  __syncthreads();

#pragma unroll
  for (int i = 0; i < 4; ++i) {
    int n = t + i * 1024;
    const float4* op = (const float4*)(obs + ((size_t)b * NN + n) * DS);
    float4 o0 = op[0], o1 = op[1];
    float o[DS] = {o0.x, o0.y, o0.z, o0.w, o1.x, o1.y, o1.z, o1.w};
    float hb[HH];
#pragma unroll
    for (int j = 0; j < HH; ++j) {
      float a = sbn1[j];
#pragma unroll
      for (int k2 = 0; k2 < DS; ++k2) a += o[k2] * sWn1[k2 * HH + j];
      hb[j] = fmaxf(a, 0.f);
    }
    float e[ENC];
#pragma unroll
    for (int c = 0; c < ENC; ++c) {
      float a = sbn2[c];
#pragma unroll
      for (int j = 0; j < HH; ++j) a += hb[j] * sWn2[j * ENC + c];
      e[c] = a;
    }
    uint4 pk;
    pk.x = __builtin_bit_cast(uint32_t, __builtin_amdgcn_cvt_pkrtz(e[0], e[1]));
    pk.y = __builtin_bit_cast(uint32_t, __builtin_amdgcn_cvt_pkrtz(e[2], e[3]));
    pk.z = __builtin_bit_cast(uint32_t, __builtin_amdgcn_cvt_pkrtz(e[4], e[5]));
    pk.w = __builtin_bit_cast(uint32_t, __builtin_amdgcn_cvt_pkrtz(e[6], e[7]));
    *(uint4*)(&xl[n * 4]) = pk;
  }
  __syncthreads();

  // ---- stage B: wave-split ----
  if (wv < 8) {
    // edge waves: 1024 edges each, 16/lane, ILP groups of 2
    float wvv[ES * ENC], bvv[ENC];
#pragma unroll
    for (int i = 0; i < ES * ENC; ++i) wvv[i] = Wee[i];
#pragma unroll
    for (int c = 0; c < ENC; ++c) bvv[c] = bee[c];

    const int*    ibs = eidx + (size_t)b * 2 * EE + (size_t)s * EPB + wv * 1024;
    const int*    ibd = ibs + EE;
    const float4* ab4 = (const float4*)eattr + (size_t)b * EE + (size_t)s * EPB + wv * 1024;

#pragma unroll
    for (int g = 0; g < 8; ++g) {
      int s_[2], d_[2];
      float4 a_[2];
      uint4 xp_[2];
#pragma unroll
      for (int u = 0; u < 2; ++u) {
        int k = g * 128 + u * 64 + lane;
        s_[u] = ibs[k]; d_[u] = ibd[k];
      }
#pragma unroll
      for (int u = 0; u < 2; ++u) a_[u] = ab4[g * 128 + u * 64 + lane];
#pragma unroll
      for (int u = 0; u < 2; ++u) xp_[u] = *(const uint4*)(&xl[s_[u] * 4]);
#pragma unroll
      for (int u = 0; u < 2; ++u) {
        half2_t h0 = __builtin_bit_cast(half2_t, xp_[u].x);
        half2_t h1 = __builtin_bit_cast(half2_t, xp_[u].y);
        half2_t h2 = __builtin_bit_cast(half2_t, xp_[u].z);
        half2_t h3 = __builtin_bit_cast(half2_t, xp_[u].w);
        float xv[ENC] = {(float)h0[0], (float)h0[1], (float)h1[0], (float)h1[1],
                         (float)h2[0], (float)h2[1], (float)h3[0], (float)h3[1]};
        float av[ES] = {a_[u].x, a_[u].y, a_[u].z, a_[u].w};
        float m[ENC];
#pragma unroll
        for (int c = 0; c < ENC; ++c) {
          float ea = bvv[c];
#pragma unroll
          for (int i2 = 0; i2 < ES; ++i2) ea += av[i2] * wvv[i2 * ENC + c];
          m[c] = fmaxf(xv[c] + ea, 0.f);
        }
        uint32_t base = (uint32_t)(uintptr_t)(&sagg[d_[u]]);
#pragma unroll
        for (int cp = 0; cp < 4; ++cp) {
          half2_t pk = __builtin_amdgcn_cvt_pkrtz(m[2 * cp], m[2 * cp + 1]);
          uint32_t pku = __builtin_bit_cast(uint32_t, pk);
          uint32_t addr = base + (uint32_t)(cp * NN * 4);
          asm volatile("ds_pk_add_f16 %0, %1" :: "v"(addr), "v"(pku) : "memory");
        }
      }
    }
  } else {
    // critic waves: unit uw covers 512 rows of batch cb; 8 rows/lane
    int uw = p * 8 + (wv - 8);            // 0..2047
    int cb = uw >> 6, q = uw & 63;
    const float* ob = obsf + (size_t)cb * NI;
    float acc[HH];
#pragma unroll
    for (int j = 0; j < HH; ++j) acc[j] = 0.f;
#pragma unroll
    for (int i = 0; i < 8; ++i) {
      int r = q * 512 + i * 64 + lane;
      float v = ob[r];
      const float4* wr = (const float4*)(Wc1 + (size_t)r * HH);
      float4 w0 = wr[0], w1 = wr[1], w2 = wr[2], w3 = wr[3];
      acc[0]  += v * w0.x; acc[1]  += v * w0.y; acc[2]  += v * w0.z; acc[3]  += v * w0.w;
      acc[4]  += v * w1.x; acc[5]  += v * w1.y; acc[6]  += v * w1.z; acc[7]  += v * w1.w;
      acc[8]  += v * w2.x; acc[9]  += v * w2.y; acc[10] += v * w2.z; acc[11] += v * w2.w;
      acc[12] += v * w3.x; acc[13] += v * w3.y; acc[14] += v * w3.z; acc[15] += v * w3.w;
    }
#pragma unroll
    for (int j = 0; j < HH; ++j) {
#pragma unroll
      for (int mres = 1; mres < 64; mres <<= 1) acc[j] += __shfl_xor(acc[j], mres, 64);
    }
    if (lane < HH) hpart[(size_t)uw * HH + lane] = acc[lane];
  }
  __syncthreads();

  // ---- stage C: flush agg partial as f16x2 words + x (s==0 only) ----
  uint4* pb = partial + (size_t)L * NN;
#pragma unroll
  for (int i = 0; i < 4; ++i) {
    int n = t + i * 1024;
    pb[n] = make_uint4(sagg[0 * NN + n], sagg[1 * NN + n],
                       sagg[2 * NN + n], sagg[3 * NN + n]);
  }
  if (s == 0) {
    uint4* xg4 = (uint4*)xg + (size_t)b * NN;
#pragma unroll
    for (int i = 0; i < 4; ++i) {
      int n = t + i * 1024;
      xg4[n] = *(uint4*)(&xl[n * 4]);
    }
  }
}

// ============ Kernel 2: actor head (blocks 0..511) + critic finish (block 512) ============
__global__ __launch_bounds__(256) void k_tail(
    const uint32_t* __restrict__ xg, const uint4* __restrict__ partial,
    const float* __restrict__ Wa1, const float* __restrict__ ba1,
    const float* __restrict__ Wa2, const float* __restrict__ ba2,
    const float* __restrict__ hpart,
    const float* __restrict__ bc1,
    const float* __restrict__ Wc2, const float* __restrict__ bc2,
    float* __restrict__ out) {
  int t = threadIdx.x;
  if (blockIdx.x == 512) {
    if (t < BB) {
      int b = t;
      float hsum[HH];
#pragma unroll
      for (int j = 0; j < HH; ++j) hsum[j] = bc1[j];
      for (int u = 0; u < 64; ++u) {
        const float* hp = hpart + (size_t)(b * 64 + u) * HH;
#pragma unroll
        for (int j = 0; j < HH; ++j) hsum[j] += hp[j];
      }
      float val = bc2[0];
#pragma unroll
      for (int j = 0; j < HH; ++j) val += fmaxf(hsum[j], 0.f) * Wc2[j];
      out[(size_t)b * ROW + (ROW - 1)] = val;
    }
    return;
  }
  __shared__ float sW1[ENC * HH], sb1[HH], sW2[HH * OUTC], sb2[OUTC];
  if (t < ENC * HH)  sW1[t] = Wa1[t];
  if (t < HH)        sb1[t] = ba1[t];
  if (t < HH * OUTC) sW2[t] = Wa2[t];
  if (t < OUTC)      sb2[t] = ba2[t];
  __syncthreads();
  int gid = blockIdx.x * 256 + t;
  int b = gid >> 12;                         // N = 4096
  int n = gid & (NN - 1);

  uint4 xp = ((const uint4*)xg)[gid];
  half2_t x0 = __builtin_bit_cast(half2_t, xp.x);
  half2_t x1 = __builtin_bit_cast(half2_t, xp.y);
  half2_t x2 = __builtin_bit_cast(half2_t, xp.z);
  half2_t x3 = __builtin_bit_cast(half2_t, xp.w);
  float v[ENC] = {(float)x0[0], (float)x0[1], (float)x1[0], (float)x1[1],
                  (float)x2[0], (float)x2[1], (float)x3[0], (float)x3[1]};
  const uint4* pb = partial + (size_t)(b * ESPLIT) * NN + n;
#pragma unroll
  for (int s = 0; s < ESPLIT; ++s) {
    uint4 pw = pb[(size_t)s * NN];
    half2_t p0 = __builtin_bit_cast(half2_t, pw.x);
    half2_t p1 = __builtin_bit_cast(half2_t, pw.y);
    half2_t p2 = __builtin_bit_cast(half2_t, pw.z);
    half2_t p3 = __builtin_bit_cast(half2_t, pw.w);
    v[0] += (float)p0[0]; v[1] += (float)p0[1];
    v[2] += (float)p1[0]; v[3] += (float)p1[1];
    v[4] += (float)p2[0]; v[5] += (float)p2[1];
    v[6] += (float)p3[0]; v[7] += (float)p3[1];
  }

  float hb[HH];
#pragma unroll
  for (int j = 0; j < HH; ++j) {
    float a = sb1[j];
#pragma unroll
    for (int i = 0; i < ENC; ++i) a += v[i] * sW1[i * HH + j];
    hb[j] = fmaxf(a, 0.f);
  }
  float o[OUTC];
#pragma unroll
  for (int c = 0; c < OUTC; ++c) {
    float a = sb2[c];
#pragma unroll
    for (int j = 0; j < HH; ++j) a += hb[j] * sW2[j * OUTC + c];
    o[c] = a;
  }
  if (n > 0) {
    float* op = out + (size_t)b * ROW + (size_t)(n - 1) * OUTC;
    op[0] = o[0]; op[1] = o[1]; op[2] = o[2]; op[3] = o[3];
  }
}

extern "C" void kernel_launch(void* const* d_in, const int* in_sizes, int n_in,
                              void* d_out, int out_size, void* d_ws, size_t ws_size,
                              hipStream_t stream) {
  const float* agent_obs  = (const float*)d_in[0];
  const float* edge_attr  = (const float*)d_in[1];
  const float* obs_flat   = (const float*)d_in[2];
  const int*   edge_index = (const int*)d_in[3];
  const float* W_ne1 = (const float*)d_in[4];
  const float* b_ne1 = (const float*)d_in[5];
  const float* W_ne2 = (const float*)d_in[6];
  const float* b_ne2 = (const float*)d_in[7];
  const float* W_ee  = (const float*)d_in[8];
  const float* b_ee  = (const float*)d_in[9];
  const float* W_a1  = (const float*)d_in[10];
  const float* b_a1  = (const float*)d_in[11];
  const float* W_a2  = (const float*)d_in[12];
  const float* b_a2  = (const float*)d_in[13];
  const float* W_c1  = (const float*)d_in[14];
  const float* b_c1  = (const float*)d_in[15];
  const float* W_c2  = (const float*)d_in[16];
  const float* b_c2  = (const float*)d_in[17];
  float* out = (float*)d_out;

  uint4*    partial = (uint4*)d_ws;                                  // 16 MB
  uint32_t* xg      = (uint32_t*)(partial + (size_t)BB * ESPLIT * NN);  // 2 MB
  float*    hpart   = (float*)(xg + (size_t)BB * NN * 4);            // 128 KB

  k_mega<<<dim3(BB * ESPLIT), dim3(1024), 0, stream>>>(
      agent_obs, W_ne1, b_ne1, W_ne2, b_ne2,
      edge_attr, edge_index, W_ee, b_ee,
      obs_flat, W_c1, partial, xg, hpart);
  k_tail<<<dim3(513), dim3(256), 0, stream>>>(
      xg, partial, W_a1, b_a1, W_a2, b_a2, hpart, b_c1, W_c2, b_c2, out);
}

// Round 13
// 159.324 us; speedup vs baseline: 2.3630x; 2.3105x over previous
//
#include <hip/hip_runtime.h>

#define BB 32
#define NN 4096
#define EE 65536
#define DS 8
#define ES 4
#define ENC 8
#define HH 16
#define OUTC 4
#define NI (NN * DS)
#define ROW (NN * OUTC - OUTC + 1)   // 16381 per-batch output row length
#define CSPLIT 16                    // critic K-dim split
#define CCHUNK (NI / CSPLIT)         // 2048
#define ESPLIT 8                     // edge-chunk splits per batch
#define EPB (EE / ESPLIT)            // 8192 edges per block
#define FIXS 1024.0f                 // fixed-point scale (F=10)
#define FIXI (1.0f / 1024.0f)

// ============ Kernel A: node encoder (blocks 0..511) + critic partials (512..1023) ============
__global__ __launch_bounds__(256) void k_fusedA(
    const float* __restrict__ obs,
    const float* __restrict__ Wne1, const float* __restrict__ bne1,
    const float* __restrict__ Wne2, const float* __restrict__ bne2,
    const float* __restrict__ obsf, const float* __restrict__ Wc1,
    float* __restrict__ x, float* __restrict__ hpart) {
  __shared__ float sW1[DS * HH], sb1[HH], sW2[HH * ENC], sb2[ENC];
  __shared__ float red[4][HH];
  int t = threadIdx.x;

  if (blockIdx.x < 512) {
    // ---- node encoder ----
    if (t < DS * HH)  sW1[t] = Wne1[t];
    if (t < HH)       sb1[t] = bne1[t];
    if (t < HH * ENC) sW2[t] = Wne2[t];
    if (t < ENC)      sb2[t] = bne2[t];
    __syncthreads();
    int gid = blockIdx.x * 256 + t;        // node id in [0, B*N)

    const float4* op = (const float4*)(obs + (size_t)gid * DS);
    float4 o0 = op[0], o1 = op[1];
    float o[DS] = {o0.x, o0.y, o0.z, o0.w, o1.x, o1.y, o1.z, o1.w};

    float hb[HH];
#pragma unroll
    for (int j = 0; j < HH; ++j) {
      float a = sb1[j];
#pragma unroll
      for (int i = 0; i < DS; ++i) a += o[i] * sW1[i * HH + j];
      hb[j] = fmaxf(a, 0.f);
    }
    float e[ENC];
#pragma unroll
    for (int c = 0; c < ENC; ++c) {
      float a = sb2[c];
#pragma unroll
      for (int j = 0; j < HH; ++j) a += hb[j] * sW2[j * ENC + c];
      e[c] = a;
    }
    float4* xp = (float4*)(x + (size_t)gid * ENC);
    xp[0] = make_float4(e[0], e[1], e[2], e[3]);
    xp[1] = make_float4(e[4], e[5], e[6], e[7]);
  } else {
    // ---- critic GEMV partials: cb = (b, s) ----
    int cb = blockIdx.x - 512;
    int b = cb / CSPLIT, s = cb % CSPLIT;
    float acc[HH];
#pragma unroll
    for (int j = 0; j < HH; ++j) acc[j] = 0.f;

    const float* ob = obsf + (size_t)b * NI;
    int i0 = s * CCHUNK;
    for (int i = i0 + t; i < i0 + CCHUNK; i += 256) {
      float v = ob[i];
      const float4* wr = (const float4*)(Wc1 + (size_t)i * HH);
      float4 w0 = wr[0], w1 = wr[1], w2 = wr[2], w3 = wr[3];
      acc[0]  += v * w0.x; acc[1]  += v * w0.y; acc[2]  += v * w0.z; acc[3]  += v * w0.w;
      acc[4]  += v * w1.x; acc[5]  += v * w1.y; acc[6]  += v * w1.z; acc[7]  += v * w1.w;
      acc[8]  += v * w2.x; acc[9]  += v * w2.y; acc[10] += v * w2.z; acc[11] += v * w2.w;
      acc[12] += v * w3.x; acc[13] += v * w3.y; acc[14] += v * w3.z; acc[15] += v * w3.w;
    }
    int wid = t >> 6, lane = t & 63;
#pragma unroll
    for (int j = 0; j < HH; ++j) {
      float a = acc[j];
#pragma unroll
      for (int off = 32; off >= 1; off >>= 1) a += __shfl_down(a, off, 64);
      if (lane == 0) red[wid][j] = a;
    }
    __syncthreads();
    if (t < HH)
      hpart[(size_t)cb * HH + t] = red[0][t] + red[1][t] + red[2][t] + red[3][t];
  }
}

// ============ Kernel B: edge encode + gather + relu + packed-u64 fixed-point LDS scatter ============
// grid = BB * ESPLIT = 256 blocks, 1024 threads, 64 KB LDS.
// Messages are ReLU outputs (>= 0): 4 channels pack into one u64 as 4x16-bit unsigned
// fixed-point (F=10). 2 ds_add_u64 per edge vs r7's 4 ds_pk_add_f16 -- duration tracks
// the lane-atomic count (r5->r7: 65536->32768 ops = 97->55.5 us).
__global__ __launch_bounds__(1024, 4) void k_edge_full(
    const float* __restrict__ eattr,
    const int* __restrict__ eidx,
    const float* __restrict__ Wee, const float* __restrict__ bee,
    const float* __restrict__ x,
    uint4* __restrict__ partial) {            // [BB*ESPLIT][NN] 2x u64 (16 B/node)
  __shared__ unsigned long long sagg64[2 * NN];  // 64 KB, [cp][node], cp = channel quad
  int p = blockIdx.x;
  int L = (p & 7) * 32 + (p >> 3);            // batch b = L>>3 pinned to XCD p&7
  int b = L >> 3, s = L & 7;
  int t = threadIdx.x;

  float wv[ES * ENC], bv[ENC];                // wave-uniform -> SGPRs
#pragma unroll
  for (int i = 0; i < ES * ENC; ++i) wv[i] = Wee[i];
#pragma unroll
  for (int c = 0; c < ENC; ++c) bv[c] = bee[c];

  {
    uint4 z = make_uint4(0u, 0u, 0u, 0u);
    uint4* sz = (uint4*)sagg64;               // 4096 uint4s
#pragma unroll
    for (int i = 0; i < 4; ++i) sz[t + i * 1024] = z;
  }
  __syncthreads();

  const int*    ibs = eidx + (size_t)b * 2 * EE + (size_t)s * EPB;
  const int*    ibd = ibs + EE;
  const float4* ab4 = (const float4*)eattr + (size_t)b * EE + (size_t)s * EPB;
  const float4* xb4 = (const float4*)(x + (size_t)b * NN * ENC);

#pragma unroll
  for (int uo = 0; uo < EPB / 4096; ++uo) {   // 2 groups of 4 edges/thread
    int k = t + uo * 4096;
    int s_[4], d_[4];
    float4 a_[4];
#pragma unroll
    for (int u = 0; u < 4; ++u) { s_[u] = ibs[k + u * 1024]; d_[u] = ibd[k + u * 1024]; }
#pragma unroll
    for (int u = 0; u < 4; ++u) a_[u] = ab4[k + u * 1024];
    float4 xl[4], xh[4];
#pragma unroll
    for (int u = 0; u < 4; ++u) { xl[u] = xb4[2 * s_[u]]; xh[u] = xb4[2 * s_[u] + 1]; }
#pragma unroll
    for (int u = 0; u < 4; ++u) {
      float av[ES] = {a_[u].x, a_[u].y, a_[u].z, a_[u].w};
      float xv[ENC] = {xl[u].x, xl[u].y, xl[u].z, xl[u].w,
                       xh[u].x, xh[u].y, xh[u].z, xh[u].w};
      unsigned q[ENC];
#pragma unroll
      for (int c = 0; c < ENC; ++c) {
        float ea = bv[c];
#pragma unroll
        for (int i2 = 0; i2 < ES; ++i2) ea += av[i2] * wv[i2 * ENC + c];
        float m = fmaxf(xv[c] + ea, 0.f);
        q[c] = (unsigned)(m * FIXS + 0.5f);   // RTN to 10 frac bits, m >= 0
      }
      unsigned long long w0 =
          (unsigned long long)(q[0] | (q[1] << 16)) |
          ((unsigned long long)(q[2] | (q[3] << 16)) << 32);
      unsigned long long w1 =
          (unsigned long long)(q[4] | (q[5] << 16)) |
          ((unsigned long long)(q[6] | (q[7] << 16)) << 32);
      atomicAdd(&sagg64[d_[u]], w0);          // ds_add_u64
      atomicAdd(&sagg64[NN + d_[u]], w1);
    }
  }
  __syncthreads();

  uint4* pb = partial + (size_t)L * NN;       // raw packed partial, 16 B/node
#pragma unroll
  for (int i = 0; i < 4; ++i) {
    int n = t + i * 1024;
    unsigned long long w0 = sagg64[n], w1 = sagg64[NN + n];
    pb[n] = make_uint4((unsigned)w0, (unsigned)(w0 >> 32),
                       (unsigned)w1, (unsigned)(w1 >> 32));
  }
}

// ============ Kernel C: actor head (blocks 0..511) + critic finish (block 512) ============
__global__ __launch_bounds__(256) void k_fusedC(
    const float* __restrict__ x, const uint4* __restrict__ partial,
    const float* __restrict__ Wa1, const float* __restrict__ ba1,
    const float* __restrict__ Wa2, const float* __restrict__ ba2,
    const float* __restrict__ hpart,
    const float* __restrict__ bc1,
    const float* __restrict__ Wc2, const float* __restrict__ bc2,
    float* __restrict__ out) {
  int t = threadIdx.x;
  if (blockIdx.x == 512) {
    // ---- critic finish: one thread per batch ----
    if (t < BB) {
      int b = t;
      float val = bc2[0];
#pragma unroll
      for (int j = 0; j < HH; ++j) {
        float h = bc1[j];
        for (int s = 0; s < CSPLIT; ++s) h += hpart[(size_t)(b * CSPLIT + s) * HH + j];
        val += fmaxf(h, 0.f) * Wc2[j];
      }
      out[(size_t)b * ROW + (ROW - 1)] = val;
    }
    return;
  }
  __shared__ float sW1[ENC * HH], sb1[HH], sW2[HH * OUTC], sb2[OUTC];
  if (t < ENC * HH)  sW1[t] = Wa1[t];
  if (t < HH)        sb1[t] = ba1[t];
  if (t < HH * OUTC) sW2[t] = Wa2[t];
  if (t < OUTC)      sb2[t] = ba2[t];
  __syncthreads();
  int gid = blockIdx.x * 256 + t;
  int b = gid >> 12;                         // N = 4096
  int n = gid & (NN - 1);

  const float4* xp = (const float4*)(x + (size_t)gid * ENC);
  float4 xa = xp[0], xbv = xp[1];
  float v[ENC] = {xa.x, xa.y, xa.z, xa.w, xbv.x, xbv.y, xbv.z, xbv.w};
  const uint4* pb = partial + (size_t)(b * ESPLIT) * NN + n;
#pragma unroll
  for (int s = 0; s < ESPLIT; ++s) {
    uint4 pw = pb[(size_t)s * NN];
    v[0] += (float)(pw.x & 0xffffu) * FIXI;
    v[1] += (float)(pw.x >> 16)     * FIXI;
    v[2] += (float)(pw.y & 0xffffu) * FIXI;
    v[3] += (float)(pw.y >> 16)     * FIXI;
    v[4] += (float)(pw.z & 0xffffu) * FIXI;
    v[5] += (float)(pw.z >> 16)     * FIXI;
    v[6] += (float)(pw.w & 0xffffu) * FIXI;
    v[7] += (float)(pw.w >> 16)     * FIXI;
  }

  float hb[HH];
#pragma unroll
  for (int j = 0; j < HH; ++j) {
    float a = sb1[j];
#pragma unroll
    for (int i = 0; i < ENC; ++i) a += v[i] * sW1[i * HH + j];
    hb[j] = fmaxf(a, 0.f);
  }
  float o[OUTC];
#pragma unroll
  for (int c = 0; c < OUTC; ++c) {
    float a = sb2[c];
#pragma unroll
    for (int j = 0; j < HH; ++j) a += hb[j] * sW2[j * OUTC + c];
    o[c] = a;
  }
  if (n > 0) {
    float* op = out + (size_t)b * ROW + (size_t)(n - 1) * OUTC;
    op[0] = o[0]; op[1] = o[1]; op[2] = o[2]; op[3] = o[3];
  }
}

extern "C" void kernel_launch(void* const* d_in, const int* in_sizes, int n_in,
                              void* d_out, int out_size, void* d_ws, size_t ws_size,
                              hipStream_t stream) {
  const float* agent_obs  = (const float*)d_in[0];
  const float* edge_attr  = (const float*)d_in[1];
  const float* obs_flat   = (const float*)d_in[2];
  const int*   edge_index = (const int*)d_in[3];
  const float* W_ne1 = (const float*)d_in[4];
  const float* b_ne1 = (const float*)d_in[5];
  const float* W_ne2 = (const float*)d_in[6];
  const float* b_ne2 = (const float*)d_in[7];
  const float* W_ee  = (const float*)d_in[8];
  const float* b_ee  = (const float*)d_in[9];
  const float* W_a1  = (const float*)d_in[10];
  const float* b_a1  = (const float*)d_in[11];
  const float* W_a2  = (const float*)d_in[12];
  const float* b_a2  = (const float*)d_in[13];
  const float* W_c1  = (const float*)d_in[14];
  const float* b_c1  = (const float*)d_in[15];
  const float* W_c2  = (const float*)d_in[16];
  const float* b_c2  = (const float*)d_in[17];
  float* out = (float*)d_out;

  float* x_buf   = (float*)d_ws;                               // B*N*ENC f32 = 4 MB
  uint4* partial = (uint4*)(x_buf + (size_t)BB * NN * ENC);    // B*8*N*16B   = 16 MB
  float* hpart   = (float*)(partial + (size_t)BB * ESPLIT * NN); // 32 KB

  k_fusedA<<<dim3(1024), dim3(256), 0, stream>>>(
      agent_obs, W_ne1, b_ne1, W_ne2, b_ne2, obs_flat, W_c1, x_buf, hpart);
  k_edge_full<<<dim3(BB * ESPLIT), dim3(1024), 0, stream>>>(
      edge_attr, edge_index, W_ee, b_ee, x_buf, partial);
  k_fusedC<<<dim3(513), dim3(256), 0, stream>>>(
      x_buf, partial, W_a1, b_a1, W_a2, b_a2, hpart, b_c1, W_c2, b_c2, out);
}